// Round 1
// baseline (186.254 us; speedup 1.0000x reference)
//
#include <hip/hip_runtime.h>
#include <hip/hip_bf16.h>
#include <stdint.h>

#define D_MODEL 1024
#define BM 128
#define BN 128
#define BK 32

typedef __attribute__((ext_vector_type(4))) float  f32x4;
typedef __attribute__((ext_vector_type(8))) __bf16 bf16x8;
typedef __attribute__((ext_vector_type(8))) unsigned short u16x8;
typedef __attribute__((ext_vector_type(4))) unsigned short u16x4;

// ---------- helpers ----------

// monotonic float->uint map so unsigned atomicMax == float max (handles negatives exactly)
__device__ __forceinline__ unsigned order_map(float x) {
    unsigned u = __float_as_uint(x);
    return (u & 0x80000000u) ? ~u : (u | 0x80000000u);
}
__device__ __forceinline__ float order_unmap(unsigned m) {
    unsigned b = (m & 0x80000000u) ? (m & 0x7fffffffu) : ~m;
    return __uint_as_float(b);
}
// f32 -> bf16 bits, round-to-nearest-even
__device__ __forceinline__ unsigned short f2bf(float f) {
    unsigned u = __float_as_uint(f);
    u += 0x7fffu + ((u >> 16) & 1u);
    return (unsigned short)(u >> 16);
}

// ---------- kernels ----------

__global__ void init_u32(unsigned* __restrict__ p, int n) {
    int i = blockIdx.x * blockDim.x + threadIdx.x;
    if (i < n) p[i] = 0u;   // order_map minimum
}

// column max over rows (slab-parallel, atomic combine). grid=(cols/256, slabs)
__global__ void colmax_kernel(const float* __restrict__ src, int rows_per_slab,
                              int cols, unsigned* __restrict__ out_u) {
    int k = blockIdx.x * blockDim.x + threadIdx.x;
    const float* p = src + (size_t)blockIdx.y * rows_per_slab * cols + k;
    float m = -__builtin_inff();
#pragma unroll 4
    for (int r = 0; r < rows_per_slab; ++r)
        m = fmaxf(m, p[(size_t)r * cols]);
    atomicMax(&out_u[k], order_map(m));
}

__global__ void scale_kernel(const unsigned* __restrict__ ma_u,
                             const unsigned* __restrict__ mw_u,
                             float* __restrict__ s) {
    int k = blockIdx.x * blockDim.x + threadIdx.x;
    if (k < D_MODEL) {
        float ma = order_unmap(ma_u[k]);
        float mw = order_unmap(mw_u[k]);
        s[k] = sqrtf(ma) / sqrtf(mw);   // ALPHA = 0.5 on both sides
    }
}

// W'[j,k] = bf16( s[j] * W[j,k] / s[k] ).  grid = D rows, 256 thr, 4 elems/thr
__global__ void build_w_kernel(const float* __restrict__ W, const float* __restrict__ s,
                               unsigned short* __restrict__ Wp) {
    int j  = blockIdx.x;
    int k4 = threadIdx.x * 4;
    float sj = s[j];
    f32x4 w  = *reinterpret_cast<const f32x4*>(&W[(size_t)j * D_MODEL + k4]);
    f32x4 sk = *reinterpret_cast<const f32x4*>(&s[k4]);
    u16x4 o;
#pragma unroll
    for (int i = 0; i < 4; ++i) o[i] = f2bf(sj * w[i] / sk[i]);
    *reinterpret_cast<u16x4*>(&Wp[(size_t)j * D_MODEL + k4]) = o;
}

// out[N,D] = x[N,K] @ Wp[D,K]^T + bias.  128x128 tile, BK=32, 4 waves (2x2),
// 16x16x32 bf16 MFMA, 4x4 frags/wave. A: f32->bf16 reg-staged; B: global_load_lds x16.
__global__ __launch_bounds__(256)
void gemm_kernel(const float* __restrict__ X, const unsigned short* __restrict__ Wp,
                 const float* __restrict__ bias, float* __restrict__ out, int N) {
    __shared__ __align__(16) unsigned short As[BM][BK];   // 8 KB
    __shared__ __align__(16) unsigned short Bs[BN][BK];   // 8 KB

    // XCD-aware swizzle: consecutive blocks on one XCD iterate col-blocks fastest,
    // sharing the 512 KB X row-panel in that XCD's L2. 2048 % 8 == 0 -> bijective.
    int flat = blockIdx.x;
    int swz  = ((gridDim.x & 7) == 0)
             ? (flat & 7) * (gridDim.x >> 3) + (flat >> 3)
             : flat;
    const int nColBlk = D_MODEL / BN;   // 8
    int by = swz / nColBlk;             // row block (X panel)
    int bx = swz % nColBlk;             // col block (Wp panel)
    int row0 = by * BM;
    int col0 = bx * BN;

    int tid  = threadIdx.x;
    int wave = tid >> 6;
    int lane = tid & 63;
    int wr   = wave >> 1;            // wave row 0..1
    int wc   = wave & 1;             // wave col 0..1
    int l16  = lane & 15;
    int kseg = (lane >> 4) * 8;      // k offset of this lane's 8 elements

    f32x4 acc[4][4];
#pragma unroll
    for (int m = 0; m < 4; ++m)
#pragma unroll
        for (int n = 0; n < 4; ++n)
            acc[m][n] = (f32x4){0.f, 0.f, 0.f, 0.f};

    for (int k0 = 0; k0 < D_MODEL; k0 += BK) {
        __syncthreads();   // previous compute done before overwriting LDS

        // ---- stage A: 128x32 f32 -> bf16, 8 elems/chunk, 2 chunks/thread ----
#pragma unroll
        for (int i = 0; i < 2; ++i) {
            int c  = tid + 256 * i;      // chunk id 0..511
            int r  = c >> 2;             // row 0..127
            int kc = (c & 3) * 8;        // k offset 0/8/16/24
            const float* gp = X + (size_t)(row0 + r) * D_MODEL + k0 + kc;
            f32x4 x0 = *reinterpret_cast<const f32x4*>(gp);
            f32x4 x1 = *reinterpret_cast<const f32x4*>(gp + 4);
            u16x8 v;
#pragma unroll
            for (int e = 0; e < 4; ++e) { v[e] = f2bf(x0[e]); v[e + 4] = f2bf(x1[e]); }
            *reinterpret_cast<u16x8*>(&As[r][kc]) = v;
        }

        // ---- stage B: 128x32 bf16 via global_load_lds (16B/lane) ----
#pragma unroll
        for (int i = 0; i < 2; ++i) {
            int rbase = (i * 4 + wave) * 16;            // wave-uniform LDS row base
            int j     = rbase + (lane >> 2);            // per-lane global row
            int kc    = (lane & 3) * 8;
            const unsigned short* gsrc = Wp + (size_t)(col0 + j) * D_MODEL + k0 + kc;
            __builtin_amdgcn_global_load_lds(
                (const __attribute__((address_space(1))) void*)gsrc,
                (__attribute__((address_space(3))) void*)&Bs[rbase][0],
                16, 0, 0);
        }

        __syncthreads();   // staging (incl. vmcnt drain) complete

        // ---- compute: 8 ds_read_b128 + 16 MFMA ----
        bf16x8 afrag[4], bfrag[4];
#pragma unroll
        for (int m = 0; m < 4; ++m)
            afrag[m] = *reinterpret_cast<const bf16x8*>(&As[wr * 64 + m * 16 + l16][kseg]);
#pragma unroll
        for (int n = 0; n < 4; ++n)
            bfrag[n] = *reinterpret_cast<const bf16x8*>(&Bs[wc * 64 + n * 16 + l16][kseg]);
#pragma unroll
        for (int m = 0; m < 4; ++m)
#pragma unroll
            for (int n = 0; n < 4; ++n)
                acc[m][n] = __builtin_amdgcn_mfma_f32_16x16x32_bf16(
                    afrag[m], bfrag[n], acc[m][n], 0, 0, 0);
    }

    // ---- epilogue: C/D layout col = lane&15, row = (lane>>4)*4 + q ----
    int crow = row0 + wr * 64;
    int ccol = col0 + wc * 64;
#pragma unroll
    for (int n = 0; n < 4; ++n) {
        int col = ccol + n * 16 + l16;
        float b = bias[col];
#pragma unroll
        for (int m = 0; m < 4; ++m) {
            int r = crow + m * 16 + (lane >> 4) * 4;
#pragma unroll
            for (int q = 0; q < 4; ++q)
                out[(size_t)(r + q) * D_MODEL + col] = acc[m][n][q] + b;
        }
    }
}

// ---------- launch ----------

extern "C" void kernel_launch(void* const* d_in, const int* in_sizes, int n_in,
                              void* d_out, int out_size, void* d_ws, size_t ws_size,
                              hipStream_t stream) {
    const float* x    = (const float*)d_in[0];
    const float* w    = (const float*)d_in[1];
    const float* bias = (const float*)d_in[2];
    float* out        = (float*)d_out;
    const int N       = in_sizes[0] / D_MODEL;   // 32768

    // ws layout: [0,4K) maxact_u | [4K,8K) maxw_u | [8K,12K) s | [16K, 16K+2M) Wp bf16
    char* ws               = (char*)d_ws;
    unsigned*       ma_u   = (unsigned*)(ws);
    unsigned*       mw_u   = (unsigned*)(ws + 4096);
    float*          s      = (float*)(ws + 8192);
    unsigned short* Wp     = (unsigned short*)(ws + 16384);

    // 1) init the 2048 mapped-max accumulators (ws is poisoned; must self-init)
    init_u32<<<8, 256, 0, stream>>>((unsigned*)ws, 2048);
    // 2) per-column max of x: 64 slabs x 512 rows
    colmax_kernel<<<dim3(D_MODEL / 256, 64), 256, 0, stream>>>(x, N / 64, D_MODEL, ma_u);
    // 3) per-column max of weight: 16 slabs x 64 rows
    colmax_kernel<<<dim3(D_MODEL / 256, 16), 256, 0, stream>>>(w, D_MODEL / 16, D_MODEL, mw_u);
    // 4) s = sqrt(max_act)/sqrt(max_w)
    scale_kernel<<<D_MODEL / 256, 256, 0, stream>>>(ma_u, mw_u, s);
    // 5) W'[j,k] = bf16(s[j]*W[j,k]/s[k])
    build_w_kernel<<<D_MODEL, 256, 0, stream>>>(w, s, Wp);
    // 6) out = x @ W'^T + bias
    int nblk = (N / BM) * (D_MODEL / BN);   // 2048
    gemm_kernel<<<nblk, 256, 0, stream>>>(x, Wp, bias, out, N);
}